// Round 1
// baseline (1189.868 us; speedup 1.0000x reference)
//
#include <hip/hip_runtime.h>
#include <math.h>

#define NB_H  1024
#define NB_NH 16
#define NB_HD 64
#define NB_S  1024
#define NB_B  4

__device__ __forceinline__ float bf2f(unsigned short h) {
    union { unsigned u; float f; } un; un.u = ((unsigned)h) << 16; return un.f;
}
__device__ __forceinline__ unsigned short f2bf(float x) {
    union { float f; unsigned u; } un; un.f = x;
    unsigned r = un.u + 0x7FFFu + ((un.u >> 16) & 1u);
    return (unsigned short)(r >> 16);
}
__device__ __forceinline__ unsigned pack2bf(float a, float b) {
    return (unsigned)f2bf(a) | ((unsigned)f2bf(b) << 16);
}

// ---------------------------------------------------------------------------
// QKV projection: C[m][n] = hs[m][:] . W[:][n] + bias[n], scattered to
// head-major [B, NH, S, HD]. 128x128 tile, 8x8 micro-tile, BK=16.
// blockIdx.z selects which of {Wq,Wk,Wv}.
// ---------------------------------------------------------------------------
__global__ __launch_bounds__(256) void qkv_kernel(
    const float* __restrict__ hs,
    const float* __restrict__ Wq, const float* __restrict__ bq,
    const float* __restrict__ Wk, const float* __restrict__ bk,
    const float* __restrict__ Wv, const float* __restrict__ bv,
    float* __restrict__ qo, float* __restrict__ ko, float* __restrict__ vo)
{
    __shared__ float AsT[16][128];   // A transposed: AsT[k][m]
    __shared__ float Bs[16][128];    // Bs[k][n]

    const int t  = threadIdx.x;
    const int tx = t & 15;
    const int ty = t >> 4;
    const int n0 = blockIdx.x * 128;
    const int m0 = blockIdx.y * 128;
    const int which = blockIdx.z;
    const float* W    = (which == 0) ? Wq : (which == 1) ? Wk : Wv;
    const float* bias = (which == 0) ? bq : (which == 1) ? bk : bv;
    float* out        = (which == 0) ? qo : (which == 1) ? ko : vo;

    float acc[8][8];
#pragma unroll
    for (int i = 0; i < 8; ++i)
#pragma unroll
        for (int j = 0; j < 8; ++j) acc[i][j] = 0.f;

    for (int kk = 0; kk < NB_H; kk += 16) {
        // stage A (128 rows x 16 cols), transposed into AsT
#pragma unroll
        for (int it = 0; it < 2; ++it) {
            int idx = t + it * 256;
            int row = idx >> 2;
            int col = (idx & 3) << 2;
            const float4 a4 = *(const float4*)(hs + (size_t)(m0 + row) * NB_H + kk + col);
            AsT[col + 0][row] = a4.x;
            AsT[col + 1][row] = a4.y;
            AsT[col + 2][row] = a4.z;
            AsT[col + 3][row] = a4.w;
        }
        // stage B (16 rows x 128 cols)
#pragma unroll
        for (int it = 0; it < 2; ++it) {
            int idx = t + it * 256;
            int row = idx >> 5;
            int col = (idx & 31) << 2;
            *(float4*)&Bs[row][col] = *(const float4*)(W + (size_t)(kk + row) * NB_H + n0 + col);
        }
        __syncthreads();

#pragma unroll
        for (int p = 0; p < 16; ++p) {
            float4 a0 = *(const float4*)&AsT[p][8 * ty];
            float4 a1 = *(const float4*)&AsT[p][8 * ty + 4];
            float4 b0 = *(const float4*)&Bs[p][4 * tx];        // cols 4tx..+3
            float4 b1 = *(const float4*)&Bs[p][4 * tx + 64];   // cols 64+4tx..+3
            float av[8] = {a0.x, a0.y, a0.z, a0.w, a1.x, a1.y, a1.z, a1.w};
            float bw[8] = {b0.x, b0.y, b0.z, b0.w, b1.x, b1.y, b1.z, b1.w};
#pragma unroll
            for (int i = 0; i < 8; ++i)
#pragma unroll
                for (int j = 0; j < 8; ++j)
                    acc[i][j] += av[i] * bw[j];
        }
        __syncthreads();
    }

    // epilogue: scatter to [B, NH, S, HD]. n0 is a multiple of 128 so the two
    // 4-col groups live in heads h0 and h0+1 respectively.
    float4 bias0 = *(const float4*)(bias + n0 + 4 * tx);
    float4 bias1 = *(const float4*)(bias + n0 + 64 + 4 * tx);
    const int h0 = n0 >> 6;
#pragma unroll
    for (int i = 0; i < 8; ++i) {
        int m    = m0 + 8 * ty + i;
        int bidx = m >> 10;
        int s    = m & 1023;
        float4 c0 = {acc[i][0] + bias0.x, acc[i][1] + bias0.y,
                     acc[i][2] + bias0.z, acc[i][3] + bias0.w};
        *(float4*)(out + (((size_t)bidx * NB_NH + h0) * NB_S + s) * NB_HD + 4 * tx) = c0;
        float4 c1 = {acc[i][4] + bias1.x, acc[i][5] + bias1.y,
                     acc[i][6] + bias1.z, acc[i][7] + bias1.w};
        *(float4*)(out + (((size_t)bidx * NB_NH + (h0 + 1)) * NB_S + s) * NB_HD + 4 * tx) = c1;
    }
}

// ---------------------------------------------------------------------------
// Fused attention with relative-position bias, flash-style online softmax.
// One block per (b, h, 64-query tile); 16 key tiles of 64.
// Score thread map: (ty,tx) 16x16 grid, 4x4 micro-tile.
// PV thread map: l = t>>2 (row), c = t&3 (16-wide d slice).
// LDS: qs/ks fp32 (stride 65), v/pe/p bf16 (stride 66); p aliases pe buffer.
// Total static LDS = 59004 B.
// ---------------------------------------------------------------------------
__global__ __launch_bounds__(256) void attn_kernel(
    const float* __restrict__ q,
    const float* __restrict__ k,
    const float* __restrict__ v,
    const float* __restrict__ dist_emb,
    const float* __restrict__ hyp,
    const float* __restrict__ mask,
    float* __restrict__ out)
{
    __shared__ float qs[64][65];
    __shared__ float ks[64][65];
    __shared__ unsigned short vsb[64][66];
    __shared__ unsigned short pes[127][66];   // pe tile; rows 0..63 reused as probs
    __shared__ float alphas[64];
    __shared__ float lsums[64];

    const int t    = threadIdx.x;
    const int tx   = t & 15;
    const int ty   = t >> 4;
    const int l_pv = t >> 2;
    const int c_pv = t & 3;
    const int l0   = blockIdx.x * 64;
    const int h    = blockIdx.y;
    const int b    = blockIdx.z;

    const size_t headoff = ((size_t)b * NB_NH + h) * NB_S * NB_HD;
    const float* qb   = q + headoff;
    const float* kb   = k + headoff;
    const float* vb   = v + headoff;
    const float* hypb = hyp + (size_t)b * NB_S * NB_S;

    // load q tile (fp32)
#pragma unroll
    for (int it = 0; it < 4; ++it) {
        int idx = t + it * 256;        // float4 index 0..1023
        int row = idx >> 4;
        int col = (idx & 15) << 2;
        float4 v4 = *(const float4*)(qb + (size_t)(l0 + row) * NB_HD + col);
        qs[row][col + 0] = v4.x; qs[row][col + 1] = v4.y;
        qs[row][col + 2] = v4.z; qs[row][col + 3] = v4.w;
    }

    float m_run[4], lsum[4], o[16];
#pragma unroll
    for (int i = 0; i < 4; ++i) { m_run[i] = -INFINITY; lsum[i] = 0.f; }
#pragma unroll
    for (int i = 0; i < 16; ++i) o[i] = 0.f;

    const int delta = 4 * (ty - tx) + 63;   // pe row for (i=0,j=0)

    for (int kt = 0; kt < 16; ++kt) {
        const int r0 = kt * 64;
        // stage k tile (fp32)
#pragma unroll
        for (int it = 0; it < 4; ++it) {
            int idx = t + it * 256;
            int row = idx >> 4;
            int col = (idx & 15) << 2;
            float4 v4 = *(const float4*)(kb + (size_t)(r0 + row) * NB_HD + col);
            ks[row][col + 0] = v4.x; ks[row][col + 1] = v4.y;
            ks[row][col + 2] = v4.z; ks[row][col + 3] = v4.w;
        }
        // stage v tile (bf16)
#pragma unroll
        for (int it = 0; it < 4; ++it) {
            int idx = t + it * 256;
            int row = idx >> 4;
            int col = (idx & 15) << 2;
            float4 v4 = *(const float4*)(vb + (size_t)(r0 + row) * NB_HD + col);
            *(unsigned*)&vsb[row][col]     = pack2bf(v4.x, v4.y);
            *(unsigned*)&vsb[row][col + 2] = pack2bf(v4.z, v4.w);
        }
        // stage pe tile (bf16): 127 rows of dist_emb starting at l0-r0+960
        {
            const int pbase = l0 - r0 + 960;
            for (int idx = t; idx < 127 * 16; idx += 256) {
                int row = idx >> 4;
                int col = (idx & 15) << 2;
                float4 v4 = *(const float4*)(dist_emb + (size_t)(pbase + row) * NB_HD + col);
                *(unsigned*)&pes[row][col]     = pack2bf(v4.x, v4.y);
                *(unsigned*)&pes[row][col + 2] = pack2bf(v4.z, v4.w);
            }
        }
        __syncthreads();

        // ---- score phase: s[l][r] = q.k + q.pe + k.pe over d ----
        float acc[4][4];
#pragma unroll
        for (int i = 0; i < 4; ++i)
#pragma unroll
            for (int j = 0; j < 4; ++j) acc[i][j] = 0.f;

        for (int d = 0; d < 64; ++d) {
            float qv[4], kv[4];
#pragma unroll
            for (int i = 0; i < 4; ++i) qv[i] = qs[4 * ty + i][d];
#pragma unroll
            for (int j = 0; j < 4; ++j) kv[j] = ks[4 * tx + j][d];
#pragma unroll
            for (int i = 0; i < 4; ++i)
#pragma unroll
                for (int j = 0; j < 4; ++j) {
                    float pv = bf2f(pes[delta + i - j][d]);
                    acc[i][j] += qv[i] * kv[j] + (qv[i] + kv[j]) * pv;
                }
        }

        // scale + hyperbolic + mask
        float4 m4 = *(const float4*)(mask + (size_t)b * NB_S + r0 + 4 * tx);
        float sc[4][4];
#pragma unroll
        for (int i = 0; i < 4; ++i) {
            float4 h4 = *(const float4*)(hypb + (size_t)(l0 + 4 * ty + i) * NB_S + r0 + 4 * tx);
            sc[i][0] = acc[i][0] * 0.125f + 0.5f * h4.x + m4.x;
            sc[i][1] = acc[i][1] * 0.125f + 0.5f * h4.y + m4.y;
            sc[i][2] = acc[i][2] * 0.125f + 0.5f * h4.z + m4.z;
            sc[i][3] = acc[i][3] * 0.125f + 0.5f * h4.w + m4.w;
        }

        // online softmax stats per row (reduce across the 16 tx lanes)
        float p[4][4];
#pragma unroll
        for (int i = 0; i < 4; ++i) {
            float mx = fmaxf(fmaxf(sc[i][0], sc[i][1]), fmaxf(sc[i][2], sc[i][3]));
#pragma unroll
            for (int off = 1; off < 16; off <<= 1)
                mx = fmaxf(mx, __shfl_xor(mx, off, 64));
            float m_new = fmaxf(m_run[i], mx);
            float al    = __expf(m_run[i] - m_new);
            float rs    = 0.f;
#pragma unroll
            for (int j = 0; j < 4; ++j) {
                p[i][j] = __expf(sc[i][j] - m_new);
                rs += p[i][j];
            }
#pragma unroll
            for (int off = 1; off < 16; off <<= 1)
                rs += __shfl_xor(rs, off, 64);
            lsum[i]  = lsum[i] * al + rs;
            m_run[i] = m_new;
            if (tx == 0) alphas[4 * ty + i] = al;
        }
        __syncthreads();   // all pe reads done -> safe to overwrite with probs

        // write probs (bf16) into pes alias rows 0..63
#pragma unroll
        for (int i = 0; i < 4; ++i) {
            *(unsigned*)&pes[4 * ty + i][4 * tx]     = pack2bf(p[i][0], p[i][1]);
            *(unsigned*)&pes[4 * ty + i][4 * tx + 2] = pack2bf(p[i][2], p[i][3]);
        }
        __syncthreads();

        // ---- PV phase: o[l][d] = o*alpha + sum_r p[l][r] * v[r][d] ----
        {
            float al = alphas[l_pv];
#pragma unroll
            for (int m = 0; m < 16; ++m) o[m] *= al;
            for (int r = 0; r < 64; r += 2) {
                unsigned pw = *(const unsigned*)&pes[l_pv][r];
                float p0 = bf2f((unsigned short)(pw & 0xFFFFu));
                float p1 = bf2f((unsigned short)(pw >> 16));
                const unsigned* v0 = (const unsigned*)&vsb[r][c_pv * 16];
                const unsigned* v1 = (const unsigned*)&vsb[r + 1][c_pv * 16];
#pragma unroll
                for (int mm = 0; mm < 8; ++mm) {
                    unsigned w0 = v0[mm], w1 = v1[mm];
                    o[2 * mm]     += p0 * bf2f((unsigned short)(w0 & 0xFFFFu))
                                   + p1 * bf2f((unsigned short)(w1 & 0xFFFFu));
                    o[2 * mm + 1] += p0 * bf2f((unsigned short)(w0 >> 16))
                                   + p1 * bf2f((unsigned short)(w1 >> 16));
                }
            }
        }
        __syncthreads();   // before next tile's staging overwrites ks/vsb/pes
    }

    if (tx == 0) {
#pragma unroll
        for (int i = 0; i < 4; ++i) lsums[4 * ty + i] = lsum[i];
    }
    __syncthreads();

    {
        float inv = 1.0f / lsums[l_pv];
        float* op = out + ((size_t)b * NB_S + l0 + l_pv) * NB_H + h * NB_HD + c_pv * 16;
#pragma unroll
        for (int g = 0; g < 4; ++g) {
            float4 res = {o[4 * g] * inv, o[4 * g + 1] * inv,
                          o[4 * g + 2] * inv, o[4 * g + 3] * inv};
            *(float4*)(op + 4 * g) = res;
        }
    }
}

extern "C" void kernel_launch(void* const* d_in, const int* in_sizes, int n_in,
                              void* d_out, int out_size, void* d_ws, size_t ws_size,
                              hipStream_t stream) {
    const float* hs   = (const float*)d_in[0];
    const float* mask = (const float*)d_in[1];
    const float* hyp  = (const float*)d_in[2];
    const float* Wq   = (const float*)d_in[3];
    const float* bq   = (const float*)d_in[4];
    const float* Wk   = (const float*)d_in[5];
    const float* bk   = (const float*)d_in[6];
    const float* Wv   = (const float*)d_in[7];
    const float* bv   = (const float*)d_in[8];
    const float* de   = (const float*)d_in[9];

    float* qw = (float*)d_ws;
    float* kw = qw + (size_t)NB_B * NB_NH * NB_S * NB_HD;
    float* vw = kw + (size_t)NB_B * NB_NH * NB_S * NB_HD;

    dim3 g1(NB_H / 128, (NB_B * NB_S) / 128, 3);
    qkv_kernel<<<g1, 256, 0, stream>>>(hs, Wq, bq, Wk, bk, Wv, bv, qw, kw, vw);

    dim3 g2(NB_S / 64, NB_NH, NB_B);
    attn_kernel<<<g2, 256, 0, stream>>>(qw, kw, vw, de, hyp, mask, (float*)d_out);
}

// Round 2
// 312.741 us; speedup vs baseline: 3.8046x; 3.8046x over previous
//
#include <hip/hip_runtime.h>
#include <math.h>

#define S_SEQ 1024
#define NHEAD 16
#define HDIM  64
#define BATCH 4

typedef __attribute__((ext_vector_type(8))) short bf16x8;
typedef __attribute__((ext_vector_type(4))) float f32x4;

__device__ __forceinline__ float bf2f(unsigned short h) {
    union { unsigned u; float f; } un; un.u = ((unsigned)h) << 16; return un.f;
}
__device__ __forceinline__ unsigned short f2bf(float x) {
    union { float f; unsigned u; } un; un.f = x;
    unsigned r = un.u + 0x7FFFu + ((un.u >> 16) & 1u);
    return (unsigned short)(r >> 16);
}

// ---------------------------------------------------------------------------
// Prep 1: fp32 -> bf16 flat conversion of hidden_states and dist_emb.
// ---------------------------------------------------------------------------
#define HS_F4 1048576   // 4*1024*1024 / 4
#define PE_F4 32752     // 2047*64 / 4
__global__ __launch_bounds__(256) void conv_kernel(
    const float* __restrict__ hs, const float* __restrict__ de,
    unsigned short* __restrict__ hsb, unsigned short* __restrict__ peb)
{
    int i = blockIdx.x * 256 + threadIdx.x;
    if (i < HS_F4) {
        float4 v = ((const float4*)hs)[i];
        uint2 o;
        o.x = (unsigned)f2bf(v.x) | ((unsigned)f2bf(v.y) << 16);
        o.y = (unsigned)f2bf(v.z) | ((unsigned)f2bf(v.w) << 16);
        *(uint2*)(hsb + 4 * (size_t)i) = o;
    } else if (i < HS_F4 + PE_F4) {
        int j = i - HS_F4;
        float4 v = ((const float4*)de)[j];
        uint2 o;
        o.x = (unsigned)f2bf(v.x) | ((unsigned)f2bf(v.y) << 16);
        o.y = (unsigned)f2bf(v.z) | ((unsigned)f2bf(v.w) << 16);
        *(uint2*)(peb + 4 * (size_t)j) = o;
    }
}

// ---------------------------------------------------------------------------
// Prep 2: transpose+convert Wq/Wk/Wv (fp32 [k][n]) -> bf16 WT [n][k].
// 64x64 tiles through LDS (stride 67 floats: 2-way max on both sides).
// ---------------------------------------------------------------------------
__global__ __launch_bounds__(256) void wtrans_kernel(
    const float* __restrict__ Wq, const float* __restrict__ Wk,
    const float* __restrict__ Wv, unsigned short* __restrict__ wt)
{
    __shared__ float tl[64 * 67];
    const int which = blockIdx.z;
    const float* W = (which == 0) ? Wq : (which == 1) ? Wk : Wv;
    unsigned short* out = wt + (size_t)which * 1024 * 1024;
    const int k0 = blockIdx.x * 64, n0 = blockIdx.y * 64;
    const int t = threadIdx.x;

#pragma unroll
    for (int it = 0; it < 4; ++it) {
        int idx = t + it * 256;          // 0..1023 float4
        int kr = idx >> 4;
        int c4 = (idx & 15) << 2;
        float4 v = *(const float4*)(W + (size_t)(k0 + kr) * 1024 + n0 + c4);
        tl[kr * 67 + c4 + 0] = v.x; tl[kr * 67 + c4 + 1] = v.y;
        tl[kr * 67 + c4 + 2] = v.z; tl[kr * 67 + c4 + 3] = v.w;
    }
    __syncthreads();
#pragma unroll
    for (int it = 0; it < 2; ++it) {
        int idx = t + it * 256;          // 0..511 (uint4 outputs)
        int nr = idx >> 3;
        int k8 = (idx & 7) << 3;
        unsigned short r[8];
#pragma unroll
        for (int e = 0; e < 8; ++e) r[e] = f2bf(tl[(k8 + e) * 67 + nr]);
        uint4 o;
        o.x = (unsigned)r[0] | ((unsigned)r[1] << 16);
        o.y = (unsigned)r[2] | ((unsigned)r[3] << 16);
        o.z = (unsigned)r[4] | ((unsigned)r[5] << 16);
        o.w = (unsigned)r[6] | ((unsigned)r[7] << 16);
        *(uint4*)(out + (size_t)(n0 + nr) * 1024 + k0 + k8) = o;
    }
}

// ---------------------------------------------------------------------------
// QKV GEMM (bf16 MFMA): C = hsb @ W + b, scattered bf16 to [B,NH,S,HD].
// 128x128 tile, BK=32, 4 waves each 64x64 (4x4 of 16x16x32 MFMA).
// ---------------------------------------------------------------------------
__global__ __launch_bounds__(256) void qkv_mfma_kernel(
    const unsigned short* __restrict__ hsb, const unsigned short* __restrict__ wt,
    const float* __restrict__ bq, const float* __restrict__ bk,
    const float* __restrict__ bv,
    unsigned short* __restrict__ qo, unsigned short* __restrict__ ko,
    unsigned short* __restrict__ vo)
{
    __shared__ unsigned short As[128 * 40];   // [m][k] (A-layout, k contiguous)
    __shared__ unsigned short Bs[128 * 40];   // [n][k] (B^T, from pre-transposed WT)

    const int t = threadIdx.x;
    const int lane = t & 63, w = t >> 6;
    const int l16 = lane & 15, quad = lane >> 4;
    const int wm = w >> 1, wn = w & 1;
    const int n0 = blockIdx.x * 128, m0 = blockIdx.y * 128;
    const int which = blockIdx.z;
    const unsigned short* wts = wt + (size_t)which * 1024 * 1024;
    const float* bias = (which == 0) ? bq : (which == 1) ? bk : bv;
    unsigned short* out = (which == 0) ? qo : (which == 1) ? ko : vo;

    f32x4 acc[4][4];
#pragma unroll
    for (int i = 0; i < 4; ++i)
#pragma unroll
        for (int j = 0; j < 4; ++j) acc[i][j] = (f32x4){0.f, 0.f, 0.f, 0.f};

    for (int kk = 0; kk < 1024; kk += 32) {
#pragma unroll
        for (int it = 0; it < 2; ++it) {
            int idx = t + it * 256;       // 0..511
            int row = idx >> 2;
            int c8 = (idx & 3) << 3;
            *(uint4*)&As[row * 40 + c8] =
                *(const uint4*)(hsb + (size_t)(m0 + row) * 1024 + kk + c8);
            *(uint4*)&Bs[row * 40 + c8] =
                *(const uint4*)(wts + (size_t)(n0 + row) * 1024 + kk + c8);
        }
        __syncthreads();
        bf16x8 af[4], bf[4];
#pragma unroll
        for (int i = 0; i < 4; ++i)
            af[i] = *(bf16x8*)&As[(64 * wm + 16 * i + l16) * 40 + quad * 8];
#pragma unroll
        for (int j = 0; j < 4; ++j)
            bf[j] = *(bf16x8*)&Bs[(64 * wn + 16 * j + l16) * 40 + quad * 8];
#pragma unroll
        for (int i = 0; i < 4; ++i)
#pragma unroll
            for (int j = 0; j < 4; ++j)
                acc[i][j] = __builtin_amdgcn_mfma_f32_16x16x32_bf16(
                    af[i], bf[j], acc[i][j], 0, 0, 0);
        __syncthreads();
    }

#pragma unroll
    for (int j = 0; j < 4; ++j) {
        int n = n0 + 64 * wn + 16 * j + l16;
        float bvv = bias[n];
        int hh = n >> 6, hd = n & 63;
#pragma unroll
        for (int i = 0; i < 4; ++i)
#pragma unroll
            for (int r = 0; r < 4; ++r) {
                int m = m0 + 64 * wm + 16 * i + quad * 4 + r;
                int bb = m >> 10, s = m & 1023;
                out[((size_t)(bb * NHEAD + hh) * S_SEQ + s) * HDIM + hd] =
                    f2bf(acc[i][j][r] + bvv);
            }
    }
}

// ---------------------------------------------------------------------------
// Fused attention, all-MFMA. One block per (b,h,64-query tile), 4 waves.
// Per k-tile: S=q@k^T, QD=q@pe^T, KD=k@pe^T (MFMA) -> bias gather from
// transposed QD/KD in LDS -> online softmax (stats in regs, rows owned
// consistently by quad*4+reg) -> probs bf16 -> PV MFMA.
// LDS 71680 B -> 2 blocks/CU.
// ---------------------------------------------------------------------------
__global__ __launch_bounds__(256, 2) void attn_mfma_kernel(
    const unsigned short* __restrict__ qw, const unsigned short* __restrict__ kw,
    const unsigned short* __restrict__ vw, const unsigned short* __restrict__ peb,
    const float* __restrict__ hyp, const float* __restrict__ mask,
    float* __restrict__ out)
{
    __shared__ unsigned short ks[64 * 72];    // [r][d]
    __shared__ unsigned short vsb[64 * 72];   // [d][r], 16B-chunk xor-swizzled
    __shared__ unsigned short pes[128 * 72];  // [dd][d]; rows 0..63 reused as ps[l][r]
    __shared__ unsigned short QDs[128 * 68];  // QD^T [dd][l] bf16
    __shared__ unsigned short KDs[128 * 68];  // KD^T [dd][r] bf16

    const int t = threadIdx.x;
    const int lane = t & 63, w = t >> 6;
    const int l16 = lane & 15, quad = lane >> 4;
    const int l0 = blockIdx.x * 64;
    const int h = blockIdx.y, b = blockIdx.z;

    const unsigned short* qb = qw + ((size_t)(b * NHEAD + h) * S_SEQ + l0) * HDIM;
    const unsigned short* kb = kw + (size_t)(b * NHEAD + h) * S_SEQ * HDIM;
    const unsigned short* vb = vw + (size_t)(b * NHEAD + h) * S_SEQ * HDIM;
    const float* hypb  = hyp + (size_t)b * S_SEQ * S_SEQ;
    const float* maskb = mask + b * S_SEQ;

    // q A-fragments straight from global (rows 16w..16w+15, once per block)
    bf16x8 qf[2];
    qf[0] = *(const bf16x8*)(qb + (16 * w + l16) * 64 + quad * 8);
    qf[1] = *(const bf16x8*)(qb + (16 * w + l16) * 64 + 32 + quad * 8);

    if (t < 8) *(uint4*)&pes[127 * 72 + t * 8] = (uint4){0, 0, 0, 0};

    f32x4 accO[4];
#pragma unroll
    for (int j = 0; j < 4; ++j) accO[j] = (f32x4){0.f, 0.f, 0.f, 0.f};
    float m_run[4], lsum[4];
#pragma unroll
    for (int i = 0; i < 4; ++i) { m_run[i] = -INFINITY; lsum[i] = 0.f; }

    for (int kt = 0; kt < 16; ++kt) {
        const int r0 = kt * 64;
        __syncthreads();   // prior tile's ps/vsb/QD/KD reads complete
        // ---- stage k (row-major) ----
#pragma unroll
        for (int it = 0; it < 2; ++it) {
            int idx = t + it * 256;
            int row = idx >> 3, c8 = (idx & 7) << 3;
            *(uint4*)&ks[row * 72 + c8] =
                *(const uint4*)(kb + (size_t)(r0 + row) * 64 + c8);
        }
        // ---- stage v transposed [d][r], xor-swizzled 16B chunks ----
#pragma unroll
        for (int it = 0; it < 2; ++it) {
            int idx = t + it * 256;
            int vr = idx >> 3, d8 = (idx & 7) << 3;
            uint4 raw = *(const uint4*)(vb + (size_t)(r0 + vr) * 64 + d8);
            const unsigned short* pv = (const unsigned short*)&raw;
            int chunk = (((vr >> 3) ^ (d8 >> 3)) << 3) | (vr & 7);
#pragma unroll
            for (int e = 0; e < 8; ++e) vsb[(d8 + e) * 72 + chunk] = pv[e];
        }
        // ---- stage pe window rows 0..126 ----
        {
            const size_t pbase = (size_t)(l0 - r0 + 960) * 64;
            for (int idx = t; idx < 1016; idx += 256) {
                int row = idx >> 3, c8 = (idx & 7) << 3;
                *(uint4*)&pes[row * 72 + c8] = *(const uint4*)(peb + pbase + row * 64 + c8);
            }
        }
        __syncthreads();

        // ---- phase A: MFMA S, QD, KD ----
        bf16x8 kfA[2];
        kfA[0] = *(bf16x8*)&ks[(16 * w + l16) * 72 + quad * 8];
        kfA[1] = *(bf16x8*)&ks[(16 * w + l16) * 72 + 32 + quad * 8];
        f32x4 accS[4];
#pragma unroll
        for (int j = 0; j < 4; ++j) {
            bf16x8 b0 = *(bf16x8*)&ks[(16 * j + l16) * 72 + quad * 8];
            bf16x8 b1 = *(bf16x8*)&ks[(16 * j + l16) * 72 + 32 + quad * 8];
            f32x4 a = (f32x4){0.f, 0.f, 0.f, 0.f};
            a = __builtin_amdgcn_mfma_f32_16x16x32_bf16(qf[0], b0, a, 0, 0, 0);
            a = __builtin_amdgcn_mfma_f32_16x16x32_bf16(qf[1], b1, a, 0, 0, 0);
            accS[j] = a;
        }
#pragma unroll
        for (int jd = 0; jd < 8; ++jd) {
            bf16x8 p0 = *(bf16x8*)&pes[(16 * jd + l16) * 72 + quad * 8];
            bf16x8 p1 = *(bf16x8*)&pes[(16 * jd + l16) * 72 + 32 + quad * 8];
            f32x4 aq = (f32x4){0.f, 0.f, 0.f, 0.f};
            f32x4 ak = (f32x4){0.f, 0.f, 0.f, 0.f};
            aq = __builtin_amdgcn_mfma_f32_16x16x32_bf16(qf[0], p0, aq, 0, 0, 0);
            aq = __builtin_amdgcn_mfma_f32_16x16x32_bf16(qf[1], p1, aq, 0, 0, 0);
            ak = __builtin_amdgcn_mfma_f32_16x16x32_bf16(kfA[0], p0, ak, 0, 0, 0);
            ak = __builtin_amdgcn_mfma_f32_16x16x32_bf16(kfA[1], p1, ak, 0, 0, 0);
            uint2 oq, okk;
            oq.x  = (unsigned)f2bf(aq[0]) | ((unsigned)f2bf(aq[1]) << 16);
            oq.y  = (unsigned)f2bf(aq[2]) | ((unsigned)f2bf(aq[3]) << 16);
            okk.x = (unsigned)f2bf(ak[0]) | ((unsigned)f2bf(ak[1]) << 16);
            okk.y = (unsigned)f2bf(ak[2]) | ((unsigned)f2bf(ak[3]) << 16);
            *(uint2*)&QDs[(16 * jd + l16) * 68 + 16 * w + 4 * quad] = oq;
            *(uint2*)&KDs[(16 * jd + l16) * 68 + 16 * w + 4 * quad] = okk;
        }
        __syncthreads();

        // ---- phase B: gather bias, add hyp/mask, online softmax ----
        float sc[4][4];
#pragma unroll
        for (int j = 0; j < 4; ++j) {
            int r_loc = 16 * j + l16;
            float mv = maskb[r0 + r_loc];
#pragma unroll
            for (int i = 0; i < 4; ++i) {
                int ll = 16 * w + 4 * quad + i;
                int di = ll - r_loc + 63;
                float qd = bf2f(QDs[di * 68 + ll]);
                float kd = bf2f(KDs[di * 68 + r_loc]);
                float hv = hypb[(size_t)(l0 + ll) * S_SEQ + r0 + r_loc];
                sc[i][j] = (accS[j][i] + qd + kd) * 0.125f + 0.5f * hv + mv;
            }
        }
        float al[4];
#pragma unroll
        for (int i = 0; i < 4; ++i) {
            float mx = fmaxf(fmaxf(sc[i][0], sc[i][1]), fmaxf(sc[i][2], sc[i][3]));
#pragma unroll
            for (int off = 1; off < 16; off <<= 1)
                mx = fmaxf(mx, __shfl_xor(mx, off));
            float m_new = fmaxf(m_run[i], mx);
            al[i] = __expf(m_run[i] - m_new);
            float rs = 0.f;
#pragma unroll
            for (int j = 0; j < 4; ++j) {
                float p = __expf(sc[i][j] - m_new);
                sc[i][j] = p;
                rs += p;
            }
#pragma unroll
            for (int off = 1; off < 16; off <<= 1)
                rs += __shfl_xor(rs, off);
            lsum[i] = lsum[i] * al[i] + rs;
            m_run[i] = m_new;
        }
        // probs bf16 -> ps (aliases pes rows 0..63)
#pragma unroll
        for (int i = 0; i < 4; ++i)
#pragma unroll
            for (int j = 0; j < 4; ++j)
                pes[(16 * w + 4 * quad + i) * 72 + 16 * j + l16] = f2bf(sc[i][j]);
        __syncthreads();

        // ---- phase C: PV MFMA with alpha rescale ----
        bf16x8 pf[2];
        pf[0] = *(bf16x8*)&pes[(16 * w + l16) * 72 + quad * 8];
        pf[1] = *(bf16x8*)&pes[(16 * w + l16) * 72 + 32 + quad * 8];
#pragma unroll
        for (int j = 0; j < 4; ++j) {
            int d = 16 * j + l16;
            int c0 = ((quad ^ (d >> 3)) << 3);
            int c1 = (((4 + quad) ^ (d >> 3)) << 3);
            bf16x8 v0 = *(bf16x8*)&vsb[d * 72 + c0];
            bf16x8 v1 = *(bf16x8*)&vsb[d * 72 + c1];
            f32x4 o = accO[j];
#pragma unroll
            for (int r = 0; r < 4; ++r) o[r] *= al[r];
            o = __builtin_amdgcn_mfma_f32_16x16x32_bf16(pf[0], v0, o, 0, 0, 0);
            o = __builtin_amdgcn_mfma_f32_16x16x32_bf16(pf[1], v1, o, 0, 0, 0);
            accO[j] = o;
        }
    }

    // epilogue: out[b, l0+ll, h*64 + d] = O / lsum
#pragma unroll
    for (int j = 0; j < 4; ++j)
#pragma unroll
        for (int i = 0; i < 4; ++i) {
            int ll = 16 * w + 4 * quad + i;
            out[((size_t)b * S_SEQ + l0 + ll) * 1024 + h * 64 + 16 * j + l16] =
                accO[j][i] / lsum[i];
        }
}

extern "C" void kernel_launch(void* const* d_in, const int* in_sizes, int n_in,
                              void* d_out, int out_size, void* d_ws, size_t ws_size,
                              hipStream_t stream) {
    const float* hs   = (const float*)d_in[0];
    const float* mask = (const float*)d_in[1];
    const float* hyp  = (const float*)d_in[2];
    const float* Wq   = (const float*)d_in[3];
    const float* bq   = (const float*)d_in[4];
    const float* Wk   = (const float*)d_in[5];
    const float* bk   = (const float*)d_in[6];
    const float* Wv   = (const float*)d_in[7];
    const float* bv   = (const float*)d_in[8];
    const float* de   = (const float*)d_in[9];

    char* ws = (char*)d_ws;
    unsigned short* qw  = (unsigned short*)(ws);                    // 8 MB
    unsigned short* kw  = (unsigned short*)(ws + (8u << 20));       // 8 MB
    unsigned short* vw  = (unsigned short*)(ws + (16u << 20));      // 8 MB
    unsigned short* hsb = (unsigned short*)(ws + (24u << 20));      // 8 MB
    unsigned short* wt  = (unsigned short*)(ws + (32u << 20));      // 6 MB
    unsigned short* peb = (unsigned short*)(ws + (38u << 20));      // 0.25 MB

    conv_kernel<<<dim3((HS_F4 + PE_F4 + 255) / 256), 256, 0, stream>>>(hs, de, hsb, peb);
    wtrans_kernel<<<dim3(16, 16, 3), 256, 0, stream>>>(Wq, Wk, Wv, wt);
    qkv_mfma_kernel<<<dim3(8, 32, 3), 256, 0, stream>>>(hsb, wt, bq, bk, bv, qw, kw, vw);
    attn_mfma_kernel<<<dim3(16, NHEAD, BATCH), 256, 0, stream>>>(
        qw, kw, vw, peb, hyp, mask, (float*)d_out);
}

// Round 3
// 286.895 us; speedup vs baseline: 4.1474x; 1.0901x over previous
//
#include <hip/hip_runtime.h>
#include <math.h>

#define S_SEQ 1024
#define NHEAD 16
#define HDIM  64
#define BATCH 4

typedef __attribute__((ext_vector_type(8))) short bf16x8;
typedef __attribute__((ext_vector_type(4))) float f32x4;

__device__ __forceinline__ float bf2f(unsigned short h) {
    union { unsigned u; float f; } un; un.u = ((unsigned)h) << 16; return un.f;
}
__device__ __forceinline__ unsigned short f2bf(float x) {
    union { float f; unsigned u; } un; un.f = x;
    unsigned r = un.u + 0x7FFFu + ((un.u >> 16) & 1u);
    return (unsigned short)(r >> 16);
}
__device__ __forceinline__ unsigned pack2bf(float a, float b) {
    return (unsigned)f2bf(a) | ((unsigned)f2bf(b) << 16);
}
__device__ __forceinline__ void glds16(const unsigned short* g, unsigned short* l) {
    __builtin_amdgcn_global_load_lds(
        (const __attribute__((address_space(1))) void*)g,
        (__attribute__((address_space(3))) void*)l, 16, 0, 0);
}

// ---------------------------------------------------------------------------
// Prep 1: fp32 -> bf16 flat conversion of hidden_states and dist_emb.
// ---------------------------------------------------------------------------
#define HS_F4 1048576   // 4*1024*1024 / 4
#define PE_F4 32752     // 2047*64 / 4
__global__ __launch_bounds__(256) void conv_kernel(
    const float* __restrict__ hs, const float* __restrict__ de,
    unsigned short* __restrict__ hsb, unsigned short* __restrict__ peb)
{
    int i = blockIdx.x * 256 + threadIdx.x;
    if (i < HS_F4) {
        float4 v = ((const float4*)hs)[i];
        uint2 o;
        o.x = pack2bf(v.x, v.y);
        o.y = pack2bf(v.z, v.w);
        *(uint2*)(hsb + 4 * (size_t)i) = o;
    } else if (i < HS_F4 + PE_F4) {
        int j = i - HS_F4;
        float4 v = ((const float4*)de)[j];
        uint2 o;
        o.x = pack2bf(v.x, v.y);
        o.y = pack2bf(v.z, v.w);
        *(uint2*)(peb + 4 * (size_t)j) = o;
    }
}

// ---------------------------------------------------------------------------
// Prep 2: transpose+convert Wq/Wk/Wv (fp32 [k][n]) -> bf16 WT [n][k].
// ---------------------------------------------------------------------------
__global__ __launch_bounds__(256) void wtrans_kernel(
    const float* __restrict__ Wq, const float* __restrict__ Wk,
    const float* __restrict__ Wv, unsigned short* __restrict__ wt)
{
    __shared__ float tl[64 * 67];
    const int which = blockIdx.z;
    const float* W = (which == 0) ? Wq : (which == 1) ? Wk : Wv;
    unsigned short* out = wt + (size_t)which * 1024 * 1024;
    const int k0 = blockIdx.x * 64, n0 = blockIdx.y * 64;
    const int t = threadIdx.x;

#pragma unroll
    for (int it = 0; it < 4; ++it) {
        int idx = t + it * 256;
        int kr = idx >> 4;
        int c4 = (idx & 15) << 2;
        float4 v = *(const float4*)(W + (size_t)(k0 + kr) * 1024 + n0 + c4);
        tl[kr * 67 + c4 + 0] = v.x; tl[kr * 67 + c4 + 1] = v.y;
        tl[kr * 67 + c4 + 2] = v.z; tl[kr * 67 + c4 + 3] = v.w;
    }
    __syncthreads();
#pragma unroll
    for (int it = 0; it < 2; ++it) {
        int idx = t + it * 256;
        int nr = idx >> 3;
        int k8 = (idx & 7) << 3;
        unsigned short r[8];
#pragma unroll
        for (int e = 0; e < 8; ++e) r[e] = f2bf(tl[(k8 + e) * 67 + nr]);
        uint4 o;
        o.x = (unsigned)r[0] | ((unsigned)r[1] << 16);
        o.y = (unsigned)r[2] | ((unsigned)r[3] << 16);
        o.z = (unsigned)r[4] | ((unsigned)r[5] << 16);
        o.w = (unsigned)r[6] | ((unsigned)r[7] << 16);
        *(uint4*)(out + (size_t)(n0 + nr) * 1024 + k0 + k8) = o;
    }
}

// ---------------------------------------------------------------------------
// QKV GEMM, m97-style: BK=64, global_load_lds 16B staging, XOR-swizzled
// unpadded LDS (conflict-free b128 frag reads). 128x128 tile, 4 waves.
// v written TRANSPOSED per head: [b,h,d,s].
// ---------------------------------------------------------------------------
__global__ __launch_bounds__(256, 3) void qkv_mfma_kernel(
    const unsigned short* __restrict__ hsb, const unsigned short* __restrict__ wt,
    const float* __restrict__ bq, const float* __restrict__ bk,
    const float* __restrict__ bv,
    unsigned short* __restrict__ qo, unsigned short* __restrict__ ko,
    unsigned short* __restrict__ vo)
{
    __shared__ unsigned short As[128 * 64];   // [m][k], k-chunk ^ (m&7) swizzle
    __shared__ unsigned short Bs[128 * 64];

    const int t = threadIdx.x;
    const int lane = t & 63, w = t >> 6;
    const int l16 = lane & 15, quad = lane >> 4;
    const int wm = w >> 1, wn = w & 1;
    const int lrow = lane >> 3, cs = lane & 7;
    const int n0 = blockIdx.x * 128, m0 = blockIdx.y * 128;
    const int which = blockIdx.z;
    const unsigned short* wts = wt + (size_t)which * 1024 * 1024;
    const float* bias = (which == 0) ? bq : (which == 1) ? bk : bv;

    f32x4 acc[4][4];
#pragma unroll
    for (int i = 0; i < 4; ++i)
#pragma unroll
        for (int j = 0; j < 4; ++j) acc[i][j] = (f32x4){0.f, 0.f, 0.f, 0.f};

    for (int kk = 0; kk < 1024; kk += 64) {
#pragma unroll
        for (int it = 0; it < 4; ++it) {
            int mrow = 32 * w + 8 * it + lrow;
            int kch = cs ^ (mrow & 7);
            glds16(hsb + (size_t)(m0 + mrow) * 1024 + kk + kch * 8,
                   &As[(32 * w + 8 * it) * 64]);
            glds16(wts + (size_t)(n0 + mrow) * 1024 + kk + kch * 8,
                   &Bs[(32 * w + 8 * it) * 64]);
        }
        __syncthreads();

        bf16x8 af[4][2], bf[4][2];
#pragma unroll
        for (int i = 0; i < 4; ++i) {
            int am = 64 * wm + 16 * i + l16;
            int base = am * 64;
            af[i][0] = *(bf16x8*)&As[base + ((quad ^ (am & 7)) << 3)];
            af[i][1] = *(bf16x8*)&As[base + (((quad + 4) ^ (am & 7)) << 3)];
        }
#pragma unroll
        for (int j = 0; j < 4; ++j) {
            int bn = 64 * wn + 16 * j + l16;
            int base = bn * 64;
            bf[j][0] = *(bf16x8*)&Bs[base + ((quad ^ (bn & 7)) << 3)];
            bf[j][1] = *(bf16x8*)&Bs[base + (((quad + 4) ^ (bn & 7)) << 3)];
        }
#pragma unroll
        for (int i = 0; i < 4; ++i)
#pragma unroll
            for (int j = 0; j < 4; ++j) {
                acc[i][j] = __builtin_amdgcn_mfma_f32_16x16x32_bf16(
                    af[i][0], bf[j][0], acc[i][j], 0, 0, 0);
                acc[i][j] = __builtin_amdgcn_mfma_f32_16x16x32_bf16(
                    af[i][1], bf[j][1], acc[i][j], 0, 0, 0);
            }
        __syncthreads();
    }

#pragma unroll
    for (int j = 0; j < 4; ++j) {
        int n = n0 + 64 * wn + 16 * j + l16;
        float bvv = bias[n];
        int hh = n >> 6, hd = n & 63;
#pragma unroll
        for (int i = 0; i < 4; ++i) {
            int mb = m0 + 64 * wm + 16 * i + 4 * quad;
            int bb = mb >> 10, s = mb & 1023;
            if (which == 2) {
                // v transposed: [b,h,d,s]; 4 consecutive s -> one uint2
                uint2 o;
                o.x = pack2bf(acc[i][j][0] + bvv, acc[i][j][1] + bvv);
                o.y = pack2bf(acc[i][j][2] + bvv, acc[i][j][3] + bvv);
                *(uint2*)(vo + ((size_t)(bb * NHEAD + hh) * HDIM + hd) * S_SEQ + s) = o;
            } else {
                unsigned short* out = (which == 0) ? qo : ko;
#pragma unroll
                for (int r = 0; r < 4; ++r)
                    out[((size_t)(bb * NHEAD + hh) * S_SEQ + s + r) * HDIM + hd] =
                        f2bf(acc[i][j][r] + bvv);
            }
        }
    }
}

// ---------------------------------------------------------------------------
// Fused attention: Q-tile 64, K-tile 32, 4 waves, 3 blocks/CU (48.6 KB LDS).
// Ring-buffered pe window (mod 96) + incremental QD (only 32 new dist-cols
// per tile). v read from pre-transposed global [d][s]. Probs intra-wave.
// ---------------------------------------------------------------------------
__global__ __launch_bounds__(256, 3) void attn_mfma_kernel(
    const unsigned short* __restrict__ qw, const unsigned short* __restrict__ kw,
    const unsigned short* __restrict__ vtw, const unsigned short* __restrict__ peb,
    const float* __restrict__ hyp, const float* __restrict__ mask,
    float* __restrict__ out)
{
    __shared__ unsigned short ks[32 * 72];    // k tile [r][d]
    __shared__ unsigned short vT[64 * 40];    // v^T tile [d][r]
    __shared__ unsigned short pes[96 * 72];   // pe ring [slot][d]
    __shared__ unsigned short QDs[96 * 66];   // QD ring [slot][l]
    __shared__ unsigned short KDs[96 * 38];   // KD [di][r]
    __shared__ unsigned short ps[64 * 40];    // probs [l][r]

    const int t = threadIdx.x;
    const int lane = t & 63, w = t >> 6;
    const int l16 = lane & 15, quad = lane >> 4;
    const int l0 = blockIdx.x * 64;
    const int h = blockIdx.y, b = blockIdx.z;

    const unsigned short* qb = qw + ((size_t)(b * NHEAD + h) * S_SEQ + l0) * HDIM;
    const unsigned short* kb = kw + (size_t)(b * NHEAD + h) * S_SEQ * HDIM;
    const unsigned short* vtb = vtw + (size_t)(b * NHEAD + h) * HDIM * S_SEQ;
    const float* hypb = hyp + (size_t)b * S_SEQ * S_SEQ;
    const float* maskb = mask + b * S_SEQ;

    const bf16x8 qf0 = *(const bf16x8*)(qb + (16 * w + l16) * 64 + quad * 8);
    const bf16x8 qf1 = *(const bf16x8*)(qb + (16 * w + l16) * 64 + 32 + quad * 8);

    const int pb0 = l0 + 992;   // abs pe row base of window at kt=0

    // ---- prime pe ring: abs rows [pb0+32, pb0+96) ----
#pragma unroll
    for (int it = 0; it < 2; ++it) {
        int idx = t + it * 256;
        int row = idx >> 3, c8 = (idx & 7) << 3;
        int ar = pb0 + 32 + row;
        int slot = ar % 96;
        int src = ar > 2046 ? 2046 : ar;   // row 2047 staged-but-unused; clamp
        *(uint4*)&pes[slot * 72 + c8] = *(const uint4*)(peb + (size_t)src * 64 + c8);
    }
    __syncthreads();
    // ---- prime QD for those 64 dist rows ----
#pragma unroll
    for (int jd = 0; jd < 4; ++jd) {
        int slot = (pb0 + 32 + 16 * jd + l16) % 96;
        bf16x8 p0 = *(bf16x8*)&pes[slot * 72 + quad * 8];
        bf16x8 p1 = *(bf16x8*)&pes[slot * 72 + 32 + quad * 8];
        f32x4 aq = (f32x4){0.f, 0.f, 0.f, 0.f};
        aq = __builtin_amdgcn_mfma_f32_16x16x32_bf16(qf0, p0, aq, 0, 0, 0);
        aq = __builtin_amdgcn_mfma_f32_16x16x32_bf16(qf1, p1, aq, 0, 0, 0);
        int ad = slot * 66 + 16 * w + 4 * quad;
        *(unsigned*)&QDs[ad] = pack2bf(aq[0], aq[1]);
        *(unsigned*)&QDs[ad + 2] = pack2bf(aq[2], aq[3]);
    }

    f32x4 accO[4];
#pragma unroll
    for (int j = 0; j < 4; ++j) accO[j] = (f32x4){0.f, 0.f, 0.f, 0.f};
    float m_run[4], lsum[4];
#pragma unroll
    for (int i = 0; i < 4; ++i) { m_run[i] = -INFINITY; lsum[i] = 0.f; }

    int sb = pb0 % 96;   // ring slot of window base

    for (int kt = 0; kt < 32; ++kt) {
        const int r0 = 32 * kt;
        const int pb = pb0 - r0;

        // ---- stage: k (1 uint4), vT (1 uint4), 32 new pe rows (1 uint4) ----
        {
            int row = t >> 3, c8 = (t & 7) << 3;
            *(uint4*)&ks[row * 72 + c8] =
                *(const uint4*)(kb + (size_t)(r0 + row) * 64 + c8);
            int d = t >> 2, rc = (t & 3) << 3;
            *(uint4*)&vT[d * 40 + rc] =
                *(const uint4*)(vtb + (size_t)d * 1024 + r0 + rc);
            int slot = sb + row; if (slot >= 96) slot -= 96;
            *(uint4*)&pes[slot * 72 + c8] =
                *(const uint4*)(peb + (size_t)(pb + row) * 64 + c8);
        }
        __syncthreads();

        // ---- phase A: S, QD(new 32), KD MFMAs ----
        bf16x8 kfA0 = *(bf16x8*)&ks[(16 * (w & 1) + l16) * 72 + quad * 8];
        bf16x8 kfA1 = *(bf16x8*)&ks[(16 * (w & 1) + l16) * 72 + 32 + quad * 8];
        f32x4 accS[2];
#pragma unroll
        for (int j = 0; j < 2; ++j) {
            bf16x8 b0 = *(bf16x8*)&ks[(16 * j + l16) * 72 + quad * 8];
            bf16x8 b1 = *(bf16x8*)&ks[(16 * j + l16) * 72 + 32 + quad * 8];
            f32x4 a = (f32x4){0.f, 0.f, 0.f, 0.f};
            a = __builtin_amdgcn_mfma_f32_16x16x32_bf16(qf0, b0, a, 0, 0, 0);
            a = __builtin_amdgcn_mfma_f32_16x16x32_bf16(qf1, b1, a, 0, 0, 0);
            accS[j] = a;
        }
#pragma unroll
        for (int jd = 0; jd < 2; ++jd) {
            int slot = sb + 16 * jd + l16; if (slot >= 96) slot -= 96;
            bf16x8 p0 = *(bf16x8*)&pes[slot * 72 + quad * 8];
            bf16x8 p1 = *(bf16x8*)&pes[slot * 72 + 32 + quad * 8];
            f32x4 aq = (f32x4){0.f, 0.f, 0.f, 0.f};
            aq = __builtin_amdgcn_mfma_f32_16x16x32_bf16(qf0, p0, aq, 0, 0, 0);
            aq = __builtin_amdgcn_mfma_f32_16x16x32_bf16(qf1, p1, aq, 0, 0, 0);
            int ad = slot * 66 + 16 * w + 4 * quad;
            *(unsigned*)&QDs[ad] = pack2bf(aq[0], aq[1]);
            *(unsigned*)&QDs[ad + 2] = pack2bf(aq[2], aq[3]);
        }
#pragma unroll
        for (int jk = 0; jk < 3; ++jk) {
            int dd = 48 * (w >> 1) + 16 * jk + l16;
            int slot = sb + dd; if (slot >= 96) slot -= 96;
            bf16x8 p0 = *(bf16x8*)&pes[slot * 72 + quad * 8];
            bf16x8 p1 = *(bf16x8*)&pes[slot * 72 + 32 + quad * 8];
            f32x4 ak = (f32x4){0.f, 0.f, 0.f, 0.f};
            ak = __builtin_amdgcn_mfma_f32_16x16x32_bf16(kfA0, p0, ak, 0, 0, 0);
            ak = __builtin_amdgcn_mfma_f32_16x16x32_bf16(kfA1, p1, ak, 0, 0, 0);
            int ad = dd * 38 + 16 * (w & 1) + 4 * quad;
            *(unsigned*)&KDs[ad] = pack2bf(ak[0], ak[1]);
            *(unsigned*)&KDs[ad + 2] = pack2bf(ak[2], ak[3]);
        }
        __syncthreads();

        // ---- phase B: gather bias + hyp + mask, online softmax ----
        float sc[4][2], al[4];
#pragma unroll
        for (int j = 0; j < 2; ++j) {
            int r_loc = 16 * j + l16;
            float mv = maskb[r0 + r_loc];
#pragma unroll
            for (int i = 0; i < 4; ++i) {
                int ll = 16 * w + 4 * quad + i;
                int di = ll - r_loc + 31;
                int sl = sb + di; if (sl >= 96) sl -= 96;
                float qd = bf2f(QDs[sl * 66 + ll]);
                float kd = bf2f(KDs[di * 38 + r_loc]);
                float hv = hypb[(size_t)(l0 + ll) * 1024 + r0 + r_loc];
                sc[i][j] = (accS[j][i] + qd + kd) * 0.125f + 0.5f * hv + mv;
            }
        }
#pragma unroll
        for (int i = 0; i < 4; ++i) {
            float mx = fmaxf(sc[i][0], sc[i][1]);
#pragma unroll
            for (int off = 1; off < 16; off <<= 1)
                mx = fmaxf(mx, __shfl_xor(mx, off));
            float m_new = fmaxf(m_run[i], mx);
            al[i] = __expf(m_run[i] - m_new);
            float p0 = __expf(sc[i][0] - m_new);
            float p1 = __expf(sc[i][1] - m_new);
            sc[i][0] = p0; sc[i][1] = p1;
            float rs = p0 + p1;
#pragma unroll
            for (int off = 1; off < 16; off <<= 1)
                rs += __shfl_xor(rs, off);
            lsum[i] = lsum[i] * al[i] + rs;
            m_run[i] = m_new;
        }
        // probs: intra-wave rows -> no barrier needed before PV
#pragma unroll
        for (int i = 0; i < 4; ++i) {
            int ll = 16 * w + 4 * quad + i;
            ps[ll * 40 + l16] = f2bf(sc[i][0]);
            ps[ll * 40 + 16 + l16] = f2bf(sc[i][1]);
        }

        // ---- phase C: PV (K=32, one MFMA per d-fragment) ----
        bf16x8 pf = *(bf16x8*)&ps[(16 * w + l16) * 40 + quad * 8];
#pragma unroll
        for (int jf = 0; jf < 4; ++jf) {
            bf16x8 vv = *(bf16x8*)&vT[(16 * jf + l16) * 40 + quad * 8];
            f32x4 o = accO[jf];
#pragma unroll
            for (int r = 0; r < 4; ++r) o[r] *= al[r];
            o = __builtin_amdgcn_mfma_f32_16x16x32_bf16(pf, vv, o, 0, 0, 0);
            accO[jf] = o;
        }
        sb -= 32; if (sb < 0) sb += 96;
        __syncthreads();
    }

    // ---- epilogue ----
#pragma unroll
    for (int jf = 0; jf < 4; ++jf)
#pragma unroll
        for (int i = 0; i < 4; ++i) {
            int ll = 16 * w + 4 * quad + i;
            out[((size_t)b * S_SEQ + l0 + ll) * 1024 + h * 64 + 16 * jf + l16] =
                accO[jf][i] / lsum[i];
        }
}

extern "C" void kernel_launch(void* const* d_in, const int* in_sizes, int n_in,
                              void* d_out, int out_size, void* d_ws, size_t ws_size,
                              hipStream_t stream) {
    const float* hs   = (const float*)d_in[0];
    const float* mask = (const float*)d_in[1];
    const float* hyp  = (const float*)d_in[2];
    const float* Wq   = (const float*)d_in[3];
    const float* bq   = (const float*)d_in[4];
    const float* Wk   = (const float*)d_in[5];
    const float* bk   = (const float*)d_in[6];
    const float* Wv   = (const float*)d_in[7];
    const float* bv   = (const float*)d_in[8];
    const float* de   = (const float*)d_in[9];

    char* ws = (char*)d_ws;
    unsigned short* qw  = (unsigned short*)(ws);                    // 8 MB
    unsigned short* kw  = (unsigned short*)(ws + (8u << 20));       // 8 MB
    unsigned short* vtw = (unsigned short*)(ws + (16u << 20));      // 8 MB (v^T)
    unsigned short* hsb = (unsigned short*)(ws + (24u << 20));      // 8 MB
    unsigned short* wt  = (unsigned short*)(ws + (32u << 20));      // 6 MB
    unsigned short* peb = (unsigned short*)(ws + (38u << 20));      // 0.25 MB

    conv_kernel<<<dim3((HS_F4 + PE_F4 + 255) / 256), 256, 0, stream>>>(hs, de, hsb, peb);
    wtrans_kernel<<<dim3(16, 16, 3), 256, 0, stream>>>(Wq, Wk, Wv, wt);
    qkv_mfma_kernel<<<dim3(8, 32, 3), 256, 0, stream>>>(hsb, wt, bq, bk, bv, qw, kw, vtw);
    attn_mfma_kernel<<<dim3(16, NHEAD, BATCH), 256, 0, stream>>>(
        qw, kw, vtw, peb, hyp, mask, (float*)d_out);
}